// Round 7
// baseline (600.734 us; speedup 1.0000x reference)
//
#include <hip/hip_runtime.h>

// Portfolio PGD: B=4096 batches, n=104 assets.
// 1 wave per batch. R6: matvec on the MATRIX pipe — Sigma (fp16) held as
// 28 A-fragments of v_mfma_f32_16x16x32_f16 (112 VGPRs), x broadcast via
// LDS into B-fragment col 0, y returned via verified C/D layout
// (col=lane&15, row=(lane>>4)*4+reg; m89). A/B frag = 8 contiguous k per
// lane (row/col=lane&15, k=(lane>>4)*8+e; ref-checked m92/m97 pattern).
// Projection: warm-started Michelot fixed point on the VALU/DPP pipe —
// overlaps with other waves' MFMA (m114).

#define NASSET 104
#define POWER_ITERS 20
#define N_ITERS 300

typedef _Float16 v8h __attribute__((ext_vector_type(8)));
typedef float v4f __attribute__((ext_vector_type(4)));

__device__ __forceinline__ float readl(float x, int lane) {
  return __uint_as_float(__builtin_amdgcn_readlane(__float_as_uint(x), lane));
}

template <int CTRL, int ROW_MASK>
__device__ __forceinline__ float dppf(float x) {
  return __int_as_float(__builtin_amdgcn_update_dpp(
      0, __float_as_int(x), CTRL, ROW_MASK, 0xf, true));
}

// Full-wave (64-lane) sum, broadcast to all lanes via SGPR. Pure VALU pipe.
__device__ __forceinline__ float wsum(float x) {
  x += dppf<0x111, 0xf>(x);  // row_shr:1
  x += dppf<0x112, 0xf>(x);  // row_shr:2
  x += dppf<0x114, 0xf>(x);  // row_shr:4
  x += dppf<0x118, 0xf>(x);  // row_shr:8  -> lane15 of each row = row sum
  x += dppf<0x142, 0xa>(x);  // row_bcast15 into rows 1,3
  x += dppf<0x143, 0xc>(x);  // row_bcast31 into rows 2,3 -> lane63 = total
  return readl(x, 63);
}

// y = S*x via MFMA. xs must hold x (fp16, 128 entries, tail zero) on entry.
__device__ __forceinline__ void matvec_mfma(const v8h (&A)[7][4],
                                            _Float16 *xs, float *ys, int l,
                                            float &y0, float &y1) {
  const int hi = l >> 4, lo = l & 15;
  __syncthreads();  // xs writes visible (1-wave block: lgkmcnt drain)
  v4f D[7];
#pragma unroll
  for (int m = 0; m < 7; ++m) {
    D[m][0] = 0.f; D[m][1] = 0.f; D[m][2] = 0.f; D[m][3] = 0.f;
  }
#pragma unroll
  for (int kk = 0; kk < 4; ++kk) {
    // B-frag: col=lo, k=kk*32+hi*8+e. x occupies col 0 only.
    v8h bf = *reinterpret_cast<const v8h *>(xs + kk * 32 + hi * 8);
    if (lo != 0) {
#pragma unroll
      for (int e = 0; e < 8; ++e) bf[e] = (_Float16)0.f;
    }
#pragma unroll
    for (int m = 0; m < 7; ++m)
      D[m] = __builtin_amdgcn_mfma_f32_16x16x32_f16(A[m][kk], bf, D[m], 0, 0, 0);
  }
  // D col 0 lives in lanes with lo==0: rows m*16 + hi*4 + r
  if (lo == 0) {
#pragma unroll
    for (int m = 0; m < 7; ++m)
      *reinterpret_cast<v4f *>(ys + m * 16 + hi * 4) = D[m];
  }
  __syncthreads();
  y0 = ys[l];
  y1 = ys[64 + l];  // rows 104..111 = 0 (S pad); 112..127 pre-zeroed
}

__global__ __launch_bounds__(64, 2) void pgd_qp_kernel(
    const float *__restrict__ returns, const float *__restrict__ cov,
    float *__restrict__ out, int B) {
  const int b = blockIdx.x;
  if (b >= B) return;
  const int l = (int)threadIdx.x;
  const int hi = l >> 4, lo = l & 15;
  const int r0 = l;
  const int r1 = 64 + l;
  const bool ok1 = (r1 < NASSET);
  const int r1c = ok1 ? r1 : (NASSET - 1);

  __shared__ __align__(16) _Float16 xs[128];
  __shared__ __align__(16) float ys[128];
  if (l < 16) ys[112 + l] = 0.f;  // rows never written by the MFMA path

  const float *Cb = cov + (size_t)b * NASSET * NASSET;
  const float mu0 = returns[(size_t)b * NASSET + r0];
  const float mu1 = returns[(size_t)b * NASSET + r1c];

  // ---- Build A-fragments: S[i][j]=0.5*(C[i][j]+C[j][i]) + 1e-6*I, fp16 ----
  // A[m][kk]: lane holds S[m*16+lo][kk*32+hi*8+e], e=0..7.
  v8h A[7][4];
#pragma unroll
  for (int m = 0; m < 7; ++m) {
    const int row = m * 16 + lo;
#pragma unroll
    for (int kk = 0; kk < 4; ++kk) {
      const int k0 = kk * 32 + hi * 8;
      v8h af;
#pragma unroll
      for (int e = 0; e < 8; ++e) af[e] = (_Float16)0.f;
      if (row < NASSET && k0 < NASSET) {  // k0<=96 -> all 8 k valid
        const float4 p0 = *reinterpret_cast<const float4 *>(Cb + row * NASSET + k0);
        const float4 p1 = *reinterpret_cast<const float4 *>(Cb + row * NASSET + k0 + 4);
        const float rp[8] = {p0.x, p0.y, p0.z, p0.w, p1.x, p1.y, p1.z, p1.w};
#pragma unroll
        for (int e = 0; e < 8; ++e) {
          const float cp = Cb[(k0 + e) * NASSET + row];
          float s = 0.5f * (rp[e] + cp);
          if (row == k0 + e) s += 1e-6f;
          af[e] = (_Float16)s;
        }
      }
      A[m][kk] = af;
    }
  }

  // ---- Power iteration for lambda_max ----
  const float inv_n = 1.0f / (float)NASSET;
  float v0 = inv_n, v1 = ok1 ? inv_n : 0.f;
#pragma unroll 1
  for (int pi = 0; pi < POWER_ITERS; ++pi) {
    xs[l] = (_Float16)v0;
    xs[64 + l] = (_Float16)v1;  // lanes >=40 write zeros into the tail
    float y0, y1;
    matvec_mfma(A, xs, ys, l, y0, y1);
    y1 = ok1 ? y1 : 0.f;
    const float n2 = wsum(y0 * y0 + y1 * y1);
    const float inv = 1.0f / (sqrtf(n2) + 1e-12f);
    v0 = y0 * inv;
    v1 = ok1 ? (y1 * inv) : 0.f;
  }
  float z0, z1;
  {
    xs[l] = (_Float16)v0;
    xs[64 + l] = (_Float16)v1;
    matvec_mfma(A, xs, ys, l, z0, z1);
    z1 = ok1 ? z1 : 0.f;
  }
  const float lam = wsum(v0 * z0 + v1 * z1);
  const float eta = 1.0f / (2.2f * lam + 1e-8f);

  // Folded gradient constants: t = fma(-2eta, Sw, w + eta*mu)
  const float ne2 = -2.0f * eta;
  const float em0 = eta * mu0;
  const float em1 = eta * mu1;

  // ---- Projected gradient descent ----
  float w0 = inv_n, w1 = ok1 ? inv_n : 0.f;
  float theta_ws = 0.f;  // warm-start threshold carried across iterations
#pragma unroll 1
  for (int it = 0; it < N_ITERS; ++it) {
    xs[l] = (_Float16)w0;
    xs[64 + l] = (_Float16)w1;
    float y0, y1;
    matvec_mfma(A, xs, ys, l, y0, y1);
    const float t0 = fmaf(ne2, y0, w0 + em0);
    const float t1 = ok1 ? fmaf(ne2, y1, w1 + em1) : -1e30f;

    // Michelot fixed point: theta = (sum_{t>theta} t - 1)/k. Converges to
    // the unique theta* from ANY start -> warm start is exact.
    float theta = (it == 0)
                      ? (wsum(t0 + (ok1 ? t1 : 0.f)) - 1.0f) * inv_n
                      : theta_ws;
    int kp = -1;
#pragma unroll 1
    for (int r = 0; r < 32; ++r) {
      const bool c0 = t0 > theta;
      const bool c1 = t1 > theta;  // t1 = -1e30 on invalid lanes -> false
      const float s2 = wsum((c0 ? t0 : 0.f) + (c1 ? t1 : 0.f));
      const int k = __popcll(__ballot(c0)) + __popcll(__ballot(c1));
      if (k == kp) break;  // active set stable -> fixed point
      if (k == 0) {        // warm start above max(t): cold restart (rare)
        theta = (wsum(t0 + (ok1 ? t1 : 0.f)) - 1.0f) * inv_n;
        kp = -1;
        continue;
      }
      theta = (s2 - 1.0f) * __builtin_amdgcn_rcpf((float)k);
      kp = k;
    }
    theta_ws = theta;
    w0 = fmaxf(t0 - theta, 0.f);
    w1 = ok1 ? fmaxf(t1 - theta, 0.f) : 0.f;
  }

  // ---- Store ----
  out[(size_t)b * NASSET + r0] = w0;
  if (ok1) out[(size_t)b * NASSET + r1] = w1;
}

extern "C" void kernel_launch(void *const *d_in, const int *in_sizes, int n_in,
                              void *d_out, int out_size, void *d_ws,
                              size_t ws_size, hipStream_t stream) {
  const float *returns = (const float *)d_in[0];
  const float *cov = (const float *)d_in[1];
  float *out = (float *)d_out;
  const int B = in_sizes[0] / NASSET;  // 4096
  pgd_qp_kernel<<<dim3(B), dim3(64), 0, stream>>>(returns, cov, out, B);
}